// Round 10
// baseline (13817.258 us; speedup 1.0000x reference)
//
#include <hip/hip_runtime.h>
#include <hip/hip_bf16.h>
#include <stdint.h>

// LSTM: S=1024, B=64, D=1024, H=1024. fp32 in/out, bf16 MFMA internally.
// out = [Yt (S*B*H) | hT (B*H) | cT (B*H)] fp32.
// Recurrence: 128 persistent WGs x 256 thr, Wh in AGPRs. h exchanged as
// SELF-VALIDATING tagged words: u32 = (step_tag<<16)|bf16, relaxed agent
// atomics. The consumer's poll of its own input words IS the data fetch --
// no flags, no pre-publish drain, no separate detect round trip.
// 2-buffer WAW safety: tag ts+2 is only written after observing all tags
// ts+1, each of which is data-dependent on a full read of h(ts).

typedef __attribute__((ext_vector_type(8))) short bf16x8;
typedef __attribute__((ext_vector_type(4))) float f32x4;

__device__ __forceinline__ unsigned short f2bf(float f) {
    unsigned u = __builtin_bit_cast(unsigned, f);
    return (unsigned short)((u + 0x7fffu + ((u >> 16) & 1u)) >> 16);
}
__device__ __forceinline__ float fast_sigmoid(float x) {
    return __builtin_amdgcn_rcpf(1.f + __expf(-x));
}
__device__ __forceinline__ float fast_tanh(float x) {
    float xc = fminf(fmaxf(x, -9.f), 9.f);
    float e = __expf(2.f * xc);
    return (e - 1.f) * __builtin_amdgcn_rcpf(e + 1.f);
}

// ---------------- init: bias fusion + state/tag init ----------------
__global__ void init_kernel(const float* __restrict__ iiB, const float* __restrict__ hiB,
                            const float* __restrict__ ifB, const float* __restrict__ hfB,
                            const float* __restrict__ igB, const float* __restrict__ hgB,
                            const float* __restrict__ ioB, const float* __restrict__ hoB,
                            float* __restrict__ bias, unsigned int* __restrict__ hbuf,
                            float* __restrict__ c_ws) {
    int tid = blockIdx.x * 256 + threadIdx.x;   // grid 64 x 256 = 16384
    if (tid < 4096) {
        int g = tid >> 10, j = tid & 1023;
        const float* ib = (g == 0 ? iiB : g == 1 ? ifB : g == 2 ? igB : ioB);
        const float* hb = (g == 0 ? hiB : g == 1 ? hfB : g == 2 ? hgB : hoB);
        bias[tid] = ib[j] + hb[j];
    }
    for (int i = tid; i < 65536; i += 16384) {
        hbuf[i]         = 0u;          // buf0: tag 0 | bf16(0)  (= h0)
        hbuf[65536 + i] = 0xFFFF0000u; // buf1: never-matching tag
        c_ws[i] = 0.f;
    }
}

// ---------------- weights -> bf16, gate-stacked n = g*1024 + j ----------------
__global__ void prep_weights(const float* __restrict__ iiW, const float* __restrict__ hiW,
                             const float* __restrict__ ifW, const float* __restrict__ hfW,
                             const float* __restrict__ igW, const float* __restrict__ hgW,
                             const float* __restrict__ ioW, const float* __restrict__ hoW,
                             unsigned short* __restrict__ Wx, unsigned short* __restrict__ Wh) {
    int n = blockIdx.x;               // 0..4095
    int g = n >> 10, j = n & 1023;
    const float* wx = (g == 0 ? iiW : g == 1 ? ifW : g == 2 ? igW : ioW) + (size_t)j * 1024;
    const float* wh = (g == 0 ? hiW : g == 1 ? hfW : g == 2 ? hgW : hoW) + (size_t)j * 1024;
    int k = threadIdx.x * 4;
    float4 a = *(const float4*)(wx + k);
    float4 b = *(const float4*)(wh + k);
    ushort4 ra = { f2bf(a.x), f2bf(a.y), f2bf(a.z), f2bf(a.w) };
    ushort4 rb = { f2bf(b.x), f2bf(b.y), f2bf(b.z), f2bf(b.w) };
    *(ushort4*)(Wx + (size_t)n * 1024 + k) = ra;
    *(ushort4*)(Wh + (size_t)n * 1024 + k) = rb;
}

// ---------------- Xproj GEMM: C[M][.] = A[M][1024] @ Wx^T + bias ----------------
// 128x128 tile, BK=32, 4 waves each 64x64 (4x4 of 16x16x32 bf16 MFMA).
// Output column PERMUTED: gate-stacked n (= g*1024+j) lands at column j*4+g.
__global__ __launch_bounds__(256, 2) void xproj_gemm(const float* __restrict__ A,
                                                     const unsigned short* __restrict__ Wx,
                                                     const float* __restrict__ bias,
                                                     float* __restrict__ C) {
    __shared__ __align__(16) unsigned short Asm[128 * 32];  // 8KB, XOR-swizzled slots
    __shared__ __align__(16) unsigned short Bsm[128 * 32];  // 8KB
    int tid = threadIdx.x;
    int lane = tid & 63, wv = tid >> 6;
    int l15 = lane & 15, l4 = lane >> 4;
    int wrow = wv >> 1, wcol = wv & 1;
    int bn0 = blockIdx.x * 128, bm0 = blockIdx.y * 128;
    f32x4 acc[4][4] = {};

    for (int kk = 0; kk < 32; ++kk) {
        int k0 = kk * 32;
        __syncthreads();
#pragma unroll
        for (int it = 0; it < 2; ++it) {
            int tau = it * 256 + tid;
            int row = tau >> 2, slot = tau & 3;
            const float* src = A + (size_t)(bm0 + row) * 1024 + k0 + slot * 8;
            float4 x0 = *(const float4*)src;
            float4 x1 = *(const float4*)(src + 4);
            bf16x8 pk;
            pk[0] = (short)f2bf(x0.x); pk[1] = (short)f2bf(x0.y);
            pk[2] = (short)f2bf(x0.z); pk[3] = (short)f2bf(x0.w);
            pk[4] = (short)f2bf(x1.x); pk[5] = (short)f2bf(x1.y);
            pk[6] = (short)f2bf(x1.z); pk[7] = (short)f2bf(x1.w);
            int dslot = slot ^ (row & 3);
            *(bf16x8*)((char*)Asm + row * 64 + dslot * 16) = pk;
        }
#pragma unroll
        for (int it = 0; it < 2; ++it) {
            int tau = it * 256 + tid;
            int row = tau >> 2, slot = tau & 3;
            int sslot = slot ^ (row & 3);
            const unsigned short* src = Wx + (size_t)(bn0 + row) * 1024 + k0 + sslot * 8;
            char* ldsb = (char*)Bsm + it * 4096 + wv * 1024;
            __builtin_amdgcn_global_load_lds((const __attribute__((address_space(1))) void*)src,
                                             (__attribute__((address_space(3))) void*)ldsb, 16, 0, 0);
        }
        __syncthreads();
        bf16x8 af[4], bfv[4];
#pragma unroll
        for (int i = 0; i < 4; ++i) {
            int rowa = wrow * 64 + i * 16 + l15;
            int sa = l4 ^ (rowa & 3);
            af[i] = *(const bf16x8*)((const char*)Asm + rowa * 64 + sa * 16);
            int rowb = wcol * 64 + i * 16 + l15;
            int sb = l4 ^ (rowb & 3);
            bfv[i] = *(const bf16x8*)((const char*)Bsm + rowb * 64 + sb * 16);
        }
#pragma unroll
        for (int i = 0; i < 4; ++i)
#pragma unroll
            for (int j = 0; j < 4; ++j)
                acc[i][j] = __builtin_amdgcn_mfma_f32_16x16x32_bf16(af[i], bfv[j], acc[i][j], 0, 0, 0);
    }
#pragma unroll
    for (int i = 0; i < 4; ++i) {
        int m = bm0 + wrow * 64 + i * 16 + l4 * 4;
#pragma unroll
        for (int j = 0; j < 4; ++j) {
            int n = bn0 + wcol * 64 + j * 16 + l15;
            int col = (n & 1023) * 4 + (n >> 10);
            float bs = bias[n];
#pragma unroll
            for (int r = 0; r < 4; ++r)
                C[(size_t)(m + r) * 4096 + col] = acc[i][j][r] + bs;
        }
    }
}

// ---------------- persistent recurrent kernel (one chunk of T steps) ----------------
// 128 WGs x 256 thr. WG (cg, mhalf): hidden units j0=16*cg..+16, all 4 gates,
// batch rows mhalf*32..+32. Waves K-split (256 each); Wh in AGPRs.
// h words are (tag<<16)|bf16; consumers poll their own input words.
__global__ __launch_bounds__(256, 1) void lstm_steps(const float* __restrict__ xproj,
                                                     unsigned int* __restrict__ hbuf,
                                                     float* __restrict__ c_ws,
                                                     const unsigned short* __restrict__ Wh,
                                                     float* __restrict__ out,
                                                     int t0, int T) {
    __shared__ float red[8192];   // 32KB: [wv:4][32][64]
    int tid = threadIdx.x, lane = tid & 63, wv = tid >> 6;
    int l15 = lane & 15, l4 = lane >> 4;
    int wg = blockIdx.x;
    int mhalf = wg & 1;
    int cg = wg >> 1;
    int j0 = cg * 16;

    // this wave's weight fragments: K slice [wv*256, +256), 4 gates x 16 units
    bf16x8 w[8][4];
#pragma unroll
    for (int ks = 0; ks < 8; ++ks)
#pragma unroll
        for (int g = 0; g < 4; ++g) {
            int n = g * 1024 + j0 + l15;
            int k = wv * 256 + ks * 32 + l4 * 8;
            w[ks][g] = *(const bf16x8*)(Wh + (size_t)n * 1024 + k);
        }
#pragma unroll
    for (int ks = 0; ks < 8; ++ks)
#pragma unroll
        for (int g = 0; g < 4; ++g)
            asm volatile("" : "+a"(w[ks][g]));

    // persistent c state: pairs p = 2*wv + pi, (m = p>>2, r = p&3)
    float c_reg[2];
    int bq[2];
#pragma unroll
    for (int pi = 0; pi < 2; ++pi) {
        int p = wv * 2 + pi, m = p >> 2, r = p & 3;
        bq[pi] = mhalf * 32 + m * 16 + l4 * 4 + r;
        c_reg[pi] = c_ws[(size_t)bq[pi] * 1024 + j0 + l15];
    }

    // u64 element offsets for this lane's 16 tagged-h fragments (4 u64 each)
    // row(m) = mhalf*32 + m*16 + l15 ; col = wv*256 + ks*32 + l4*8
    float yv[2] = {0.f, 0.f};

    for (int tl = 0; tl < T; ++tl) {
        int ts = t0 + tl;
        int par = ts & 1;
        const unsigned long long* hb64 =
            (const unsigned long long*)(hbuf + (size_t)par * 65536);

        // xproj for this step (gate-interleaved float4; L2-warm)
        float4 xp[2];
#pragma unroll
        for (int pi = 0; pi < 2; ++pi)
            xp[pi] = *(const float4*)(xproj + (size_t)(tl * 64 + bq[pi]) * 4096 + (j0 + l15) * 4);

        // ---- poll+fetch tagged h: all 16 fragments x 4 u64 must carry tag ts ----
        unsigned long long raw[2][8][4];
        {
            unsigned tg = (unsigned)ts;
            for (;;) {
                bool ok = true;
#pragma unroll
                for (int m = 0; m < 2; ++m) {
                    size_t rb = ((size_t)(mhalf * 32 + m * 16 + l15) * 1024 + wv * 256 + l4 * 8) >> 1;
#pragma unroll
                    for (int ks = 0; ks < 8; ++ks) {
#pragma unroll
                        for (int q = 0; q < 4; ++q) {
                            unsigned long long r = __hip_atomic_load(
                                hb64 + rb + ks * 16 + q, __ATOMIC_RELAXED, __HIP_MEMORY_SCOPE_AGENT);
                            raw[m][ks][q] = r;
                            ok &= (((unsigned)(r >> 16) & 0xFFFFu) == tg) &
                                  ((unsigned)(r >> 48) == tg);
                        }
                    }
                }
                if (__ballot(ok) == ~0ull) break;
                __builtin_amdgcn_s_sleep(1);
            }
        }
        // unpack low halves -> bf16x8 fragments
        bf16x8 af[2][8];
#pragma unroll
        for (int m = 0; m < 2; ++m)
#pragma unroll
            for (int ks = 0; ks < 8; ++ks) {
                union { unsigned u[4]; bf16x8 v; } t;
#pragma unroll
                for (int q = 0; q < 4; ++q) {
                    unsigned long long r = raw[m][ks][q];
                    t.u[q] = ((unsigned)r & 0xFFFFu) | (((unsigned)(r >> 32) & 0xFFFFu) << 16);
                }
                af[m][ks] = t.v;
            }

        f32x4 acc[2][4] = {};
#pragma unroll
        for (int ks = 0; ks < 8; ++ks)
#pragma unroll
            for (int m = 0; m < 2; ++m)
#pragma unroll
                for (int g = 0; g < 4; ++g)
                    acc[m][g] = __builtin_amdgcn_mfma_f32_16x16x32_bf16(af[m][ks], w[ks][g], acc[m][g], 0, 0, 0);

        // cross-wave K reduction in LDS
#pragma unroll
        for (int m = 0; m < 2; ++m)
#pragma unroll
            for (int g = 0; g < 4; ++g)
#pragma unroll
                for (int r = 0; r < 4; ++r)
                    red[(wv * 32 + m * 16 + g * 4 + r) * 64 + lane] = acc[m][g][r];
        __syncthreads();

        // pointwise: wave wv handles pairs 2wv, 2wv+1
        unsigned ntag = (unsigned)(ts + 1) << 16;
        unsigned int* hbn = hbuf + (size_t)(par ^ 1) * 65536;
#pragma unroll
        for (int pi = 0; pi < 2; ++pi) {
            int p = wv * 2 + pi, m = p >> 2, r = p & 3;
            int b = bq[pi];
            int j = j0 + l15;
            const float* xpf = (const float*)&xp[pi];
            float pre[4];
#pragma unroll
            for (int g = 0; g < 4; ++g) {
                int s = m * 16 + g * 4 + r;
                pre[g] = red[s * 64 + lane] + red[(32 + s) * 64 + lane] +
                         red[(64 + s) * 64 + lane] + red[(96 + s) * 64 + lane] + xpf[g];
            }
            float I = fast_sigmoid(pre[0]);
            float F = fast_sigmoid(pre[1]);
            float G = fast_tanh(pre[2]);
            float O = fast_sigmoid(pre[3]);
            float c = F * c_reg[pi] + I * G;
            c_reg[pi] = c;
            float y = O * fast_tanh(c);
            yv[pi] = y;
            // self-validating publish: no drain, no flags
            __hip_atomic_store(hbn + (size_t)b * 1024 + j, ntag | (unsigned)f2bf(y),
                               __ATOMIC_RELAXED, __HIP_MEMORY_SCOPE_AGENT);
            out[(size_t)(ts * 64 + b) * 1024 + j] = y;   // fire-and-forget
        }
        __syncthreads();   // protect red[] before next step's writes
    }
    // epilogue: hT/cT + persist c
#pragma unroll
    for (int pi = 0; pi < 2; ++pi) {
        int b = bq[pi];
        int j = j0 + l15;
        if (t0 + T == 1024) {
            out[67108864u + (size_t)b * 1024 + j] = yv[pi];             // hT
            out[67108864u + 65536u + (size_t)b * 1024 + j] = c_reg[pi]; // cT
        }
        c_ws[(size_t)b * 1024 + j0 + l15] = c_reg[pi];
    }
}

extern "C" void kernel_launch(void* const* d_in, const int* in_sizes, int n_in,
                              void* d_out, int out_size, void* d_ws, size_t ws_size,
                              hipStream_t stream) {
    (void)in_sizes; (void)n_in; (void)out_size;
    const float* Xt = (const float*)d_in[0];
    const float* W[8]; for (int i = 0; i < 8; ++i) W[i] = (const float*)d_in[1 + i];
    const float* Bv[8]; for (int i = 0; i < 8; ++i) Bv[i] = (const float*)d_in[9 + i];
    float* out = (float*)d_out;
    uint8_t* ws = (uint8_t*)d_ws;

    float*          bias  = (float*)(ws + 512);
    unsigned int*   hbuf  = (unsigned int*)(ws + 16896);      // [2][64][1024] u32 tagged
    float*          c_ws  = (float*)(ws + 541184);            // [64][1024] fp32
    unsigned short* Wx    = (unsigned short*)(ws + 803328);   // [4096][1024] bf16
    unsigned short* Wh    = (unsigned short*)(ws + 9191936);  // [4096][1024] bf16
    float*          xproj = (float*)(ws + 17580544);          // [T*64][4096] fp32

    size_t avail = ws_size > 17580544 ? ws_size - 17580544 : 0;
    int T = 4;
    for (int t = 1024; t >= 4; t >>= 1)
        if ((size_t)t * 1048576ull <= avail) { T = t; break; }

    init_kernel<<<64, 256, 0, stream>>>(Bv[0], Bv[1], Bv[2], Bv[3], Bv[4], Bv[5], Bv[6], Bv[7],
                                        bias, hbuf, c_ws);
    prep_weights<<<4096, 256, 0, stream>>>(W[0], W[1], W[2], W[3], W[4], W[5], W[6], W[7], Wx, Wh);

    int nch = 1024 / T;
    for (int c = 0; c < nch; ++c) {
        xproj_gemm<<<dim3(32, T / 2), 256, 0, stream>>>(Xt + (size_t)c * T * 65536, Wx, bias, xproj);
        lstm_steps<<<128, 256, 0, stream>>>(xproj, hbuf, c_ws, Wh, out, c * T, T);
    }
}

// Round 11
// 11058.858 us; speedup vs baseline: 1.2494x; 1.2494x over previous
//
#include <hip/hip_runtime.h>
#include <hip/hip_bf16.h>
#include <stdint.h>

// LSTM: S=1024, B=64, D=1024, H=1024. fp32 in/out, bf16 MFMA internally.
// out = [Yt (S*B*H) | hT (B*H) | cT (B*H)] fp32.
// R11: revert to measured-best R7 recurrence (3070 us/chunk) + 3 probe
// dispatches that decompose the 6 us/step into sync / data / compute phases
// via their per-dispatch dur_us in rocprof. Probes touch only ws scratch.

typedef __attribute__((ext_vector_type(8))) short bf16x8;
typedef __attribute__((ext_vector_type(4))) float f32x4;

__device__ __forceinline__ unsigned short f2bf(float f) {
    unsigned u = __builtin_bit_cast(unsigned, f);
    return (unsigned short)((u + 0x7fffu + ((u >> 16) & 1u)) >> 16);
}
__device__ __forceinline__ float fast_sigmoid(float x) {
    return __builtin_amdgcn_rcpf(1.f + __expf(-x));
}
__device__ __forceinline__ float fast_tanh(float x) {
    float xc = fminf(fmaxf(x, -9.f), 9.f);
    float e = __expf(2.f * xc);
    return (e - 1.f) * __builtin_amdgcn_rcpf(e + 1.f);
}

// ---------------- init: bias fusion + state zeroing ----------------
__global__ void init_kernel(const float* __restrict__ iiB, const float* __restrict__ hiB,
                            const float* __restrict__ ifB, const float* __restrict__ hfB,
                            const float* __restrict__ igB, const float* __restrict__ hgB,
                            const float* __restrict__ ioB, const float* __restrict__ hoB,
                            float* __restrict__ bias, unsigned short* __restrict__ hbuf0,
                            float* __restrict__ c_ws, unsigned int* __restrict__ bar,
                            unsigned int* __restrict__ phbuf) {
    int tid = blockIdx.x * 256 + threadIdx.x;   // grid 64 x 256 = 16384
    if (tid < 256) bar[tid] = 0u;               // real flags [0,128) + probe flags [128,256)
    if (tid < 4096) {
        int g = tid >> 10, j = tid & 1023;
        const float* ib = (g == 0 ? iiB : g == 1 ? ifB : g == 2 ? igB : ioB);
        const float* hb = (g == 0 ? hiB : g == 1 ? hfB : g == 2 ? hgB : hoB);
        bias[tid] = ib[j] + hb[j];
    }
    for (int i = tid; i < 65536; i += 16384) {
        __hip_atomic_store(hbuf0 + i, (unsigned short)0, __ATOMIC_RELAXED, __HIP_MEMORY_SCOPE_AGENT);
        c_ws[i] = 0.f;
        phbuf[i] = 0u;    // 256KB probe h area
    }
}

// ---------------- weights -> bf16, gate-stacked n = g*1024 + j ----------------
__global__ void prep_weights(const float* __restrict__ iiW, const float* __restrict__ hiW,
                             const float* __restrict__ ifW, const float* __restrict__ hfW,
                             const float* __restrict__ igW, const float* __restrict__ hgW,
                             const float* __restrict__ ioW, const float* __restrict__ hoW,
                             unsigned short* __restrict__ Wx, unsigned short* __restrict__ Wh) {
    int n = blockIdx.x;               // 0..4095
    int g = n >> 10, j = n & 1023;
    const float* wx = (g == 0 ? iiW : g == 1 ? ifW : g == 2 ? igW : ioW) + (size_t)j * 1024;
    const float* wh = (g == 0 ? hiW : g == 1 ? hfW : g == 2 ? hgW : hoW) + (size_t)j * 1024;
    int k = threadIdx.x * 4;
    float4 a = *(const float4*)(wx + k);
    float4 b = *(const float4*)(wh + k);
    ushort4 ra = { f2bf(a.x), f2bf(a.y), f2bf(a.z), f2bf(a.w) };
    ushort4 rb = { f2bf(b.x), f2bf(b.y), f2bf(b.z), f2bf(b.w) };
    *(ushort4*)(Wx + (size_t)n * 1024 + k) = ra;
    *(ushort4*)(Wh + (size_t)n * 1024 + k) = rb;
}

// ================= PROBES (write only to ws; deterministic) =================

// Probe 1: the R6 barrier alone. dur/512 = sync cost per step.
__global__ __launch_bounds__(256, 1) void probe_sync(unsigned int* __restrict__ pbar, int T) {
    int tid = threadIdx.x;
    int mhalf = blockIdx.x & 1;
    unsigned int* mybar = pbar + mhalf * 32;
    for (int t = 0; t < T; ++t) {
        __syncthreads();
        if (tid == 0) {
            __hip_atomic_fetch_add(mybar, 1u, __ATOMIC_RELAXED, __HIP_MEMORY_SCOPE_AGENT);
            unsigned target = (unsigned)(t + 1) * 64u;
            while (__hip_atomic_load(mybar, __ATOMIC_RELAXED, __HIP_MEMORY_SCOPE_AGENT) < target)
                __builtin_amdgcn_s_sleep(1);
        }
        __syncthreads();
    }
}

// Probe 2: the h data path alone (same addresses/widths as real), serialized
// across iterations by an artificial data dependency. dur/512 = fetch+publish.
__global__ __launch_bounds__(256, 1) void probe_rt(unsigned int* __restrict__ phbuf,
                                                   float* __restrict__ sink, int T) {
    int tid = threadIdx.x, lane = tid & 63, wv = tid >> 6;
    int l15 = lane & 15, l4 = lane >> 4;
    int wg = blockIdx.x;
    int mhalf = wg & 1;
    int cg = wg >> 1;
    int j0 = cg * 16;
    unsigned acc = (unsigned)wg;
    for (int t = 0; t < T; ++t) {
        int par = t & 1;
        const unsigned short* base = (const unsigned short*)(phbuf + (size_t)par * 32768);
        unsigned dep;
        asm volatile("v_and_b32 %0, 0, %1" : "=v"(dep) : "v"(acc));  // dep==0, data-dependent
        unsigned long long s = 0;
#pragma unroll
        for (int m = 0; m < 2; ++m) {
            int row = mhalf * 32 + m * 16 + l15;
            const unsigned short* rp = base + (size_t)row * 1024 + wv * 256 + l4 * 8 + dep;
#pragma unroll
            for (int ks = 0; ks < 8; ++ks) {
                const unsigned long long* p = (const unsigned long long*)(rp + ks * 32);
                s += __hip_atomic_load(p,     __ATOMIC_RELAXED, __HIP_MEMORY_SCOPE_AGENT);
                s += __hip_atomic_load(p + 1, __ATOMIC_RELAXED, __HIP_MEMORY_SCOPE_AGENT);
            }
        }
        acc = (unsigned)s + (unsigned)(s >> 32);
        unsigned short* nb = (unsigned short*)(phbuf + (size_t)(par ^ 1) * 32768);
#pragma unroll
        for (int pi = 0; pi < 2; ++pi) {
            int p = wv * 2 + pi, m = p >> 2, r = p & 3;
            int b = mhalf * 32 + m * 16 + l4 * 4 + r;
            __hip_atomic_store(nb + (size_t)b * 1024 + j0 + l15, (unsigned short)acc,
                               __ATOMIC_RELAXED, __HIP_MEMORY_SCOPE_AGENT);
        }
    }
    sink[blockIdx.x * 256 + tid] = (float)acc;
}

// Probe 3: intra-WG compute alone (64 MFMA + LDS reduce + pointwise + 2 syncs).
__global__ __launch_bounds__(256, 1) void probe_comp(float* __restrict__ sink, int T) {
    __shared__ float red[8192];
    int tid = threadIdx.x, lane = tid & 63, wv = tid >> 6;
    int l15 = lane & 15, l4 = lane >> 4;
    bf16x8 a, b;
#pragma unroll
    for (int i = 0; i < 8; ++i) {
        a[i] = (short)f2bf(0.01f * (float)(lane + i));
        b[i] = (short)f2bf(0.02f * (float)(tid - i));
    }
    float c_reg[2] = {0.f, 0.f};
    float feed = (float)blockIdx.x;
    for (int t = 0; t < T; ++t) {
        bf16x8 av = a;
        av[0] = (short)f2bf(feed);   // cross-iteration dependency
        f32x4 acc[2][4] = {};
#pragma unroll
        for (int ks = 0; ks < 8; ++ks)
#pragma unroll
            for (int m = 0; m < 2; ++m)
#pragma unroll
                for (int g = 0; g < 4; ++g)
                    acc[m][g] = __builtin_amdgcn_mfma_f32_16x16x32_bf16(av, b, acc[m][g], 0, 0, 0);
#pragma unroll
        for (int m = 0; m < 2; ++m)
#pragma unroll
            for (int g = 0; g < 4; ++g)
#pragma unroll
                for (int r = 0; r < 4; ++r)
                    red[(wv * 32 + m * 16 + g * 4 + r) * 64 + lane] = acc[m][g][r];
        __syncthreads();
        float yv[2];
#pragma unroll
        for (int pi = 0; pi < 2; ++pi) {
            int p = wv * 2 + pi, m = p >> 2, r = p & 3;
            float pre[4];
#pragma unroll
            for (int g = 0; g < 4; ++g) {
                int s = m * 16 + g * 4 + r;
                pre[g] = red[s * 64 + lane] + red[(32 + s) * 64 + lane] +
                         red[(64 + s) * 64 + lane] + red[(96 + s) * 64 + lane] + feed;
            }
            float I = fast_sigmoid(pre[0]);
            float F = fast_sigmoid(pre[1]);
            float G = fast_tanh(pre[2]);
            float O = fast_sigmoid(pre[3]);
            float c = F * c_reg[pi] + I * G;
            c_reg[pi] = c;
            yv[pi] = O * fast_tanh(c);
        }
        feed = yv[0] + yv[1];
        __syncthreads();
    }
    sink[blockIdx.x * 256 + tid] = feed + c_reg[0] + c_reg[1];
}

// ---------------- Xproj GEMM: C[M][.] = A[M][1024] @ Wx^T + bias ----------------
// 128x128 tile, BK=32, 4 waves each 64x64 (4x4 of 16x16x32 bf16 MFMA).
// Output column PERMUTED: gate-stacked n (= g*1024+j) lands at column j*4+g.
__global__ __launch_bounds__(256, 2) void xproj_gemm(const float* __restrict__ A,
                                                     const unsigned short* __restrict__ Wx,
                                                     const float* __restrict__ bias,
                                                     float* __restrict__ C) {
    __shared__ __align__(16) unsigned short Asm[128 * 32];  // 8KB, XOR-swizzled slots
    __shared__ __align__(16) unsigned short Bsm[128 * 32];  // 8KB
    int tid = threadIdx.x;
    int lane = tid & 63, wv = tid >> 6;
    int l15 = lane & 15, l4 = lane >> 4;
    int wrow = wv >> 1, wcol = wv & 1;
    int bn0 = blockIdx.x * 128, bm0 = blockIdx.y * 128;
    f32x4 acc[4][4] = {};

    for (int kk = 0; kk < 32; ++kk) {
        int k0 = kk * 32;
        __syncthreads();
#pragma unroll
        for (int it = 0; it < 2; ++it) {
            int tau = it * 256 + tid;
            int row = tau >> 2, slot = tau & 3;
            const float* src = A + (size_t)(bm0 + row) * 1024 + k0 + slot * 8;
            float4 x0 = *(const float4*)src;
            float4 x1 = *(const float4*)(src + 4);
            bf16x8 pk;
            pk[0] = (short)f2bf(x0.x); pk[1] = (short)f2bf(x0.y);
            pk[2] = (short)f2bf(x0.z); pk[3] = (short)f2bf(x0.w);
            pk[4] = (short)f2bf(x1.x); pk[5] = (short)f2bf(x1.y);
            pk[6] = (short)f2bf(x1.z); pk[7] = (short)f2bf(x1.w);
            int dslot = slot ^ (row & 3);
            *(bf16x8*)((char*)Asm + row * 64 + dslot * 16) = pk;
        }
#pragma unroll
        for (int it = 0; it < 2; ++it) {
            int tau = it * 256 + tid;
            int row = tau >> 2, slot = tau & 3;
            int sslot = slot ^ (row & 3);
            const unsigned short* src = Wx + (size_t)(bn0 + row) * 1024 + k0 + sslot * 8;
            char* ldsb = (char*)Bsm + it * 4096 + wv * 1024;
            __builtin_amdgcn_global_load_lds((const __attribute__((address_space(1))) void*)src,
                                             (__attribute__((address_space(3))) void*)ldsb, 16, 0, 0);
        }
        __syncthreads();
        bf16x8 af[4], bfv[4];
#pragma unroll
        for (int i = 0; i < 4; ++i) {
            int rowa = wrow * 64 + i * 16 + l15;
            int sa = l4 ^ (rowa & 3);
            af[i] = *(const bf16x8*)((const char*)Asm + rowa * 64 + sa * 16);
            int rowb = wcol * 64 + i * 16 + l15;
            int sb = l4 ^ (rowb & 3);
            bfv[i] = *(const bf16x8*)((const char*)Bsm + rowb * 64 + sb * 16);
        }
#pragma unroll
        for (int i = 0; i < 4; ++i)
#pragma unroll
            for (int j = 0; j < 4; ++j)
                acc[i][j] = __builtin_amdgcn_mfma_f32_16x16x32_bf16(af[i], bfv[j], acc[i][j], 0, 0, 0);
    }
#pragma unroll
    for (int i = 0; i < 4; ++i) {
        int m = bm0 + wrow * 64 + i * 16 + l4 * 4;
#pragma unroll
        for (int j = 0; j < 4; ++j) {
            int n = bn0 + wcol * 64 + j * 16 + l15;
            int col = (n & 1023) * 4 + (n >> 10);
            float bs = bias[n];
#pragma unroll
            for (int r = 0; r < 4; ++r)
                C[(size_t)(m + r) * 4096 + col] = acc[i][j][r] + bs;
        }
    }
}

// ---------------- persistent recurrent kernel (R7 structure, measured best) ----------------
__global__ __launch_bounds__(256, 1) void lstm_steps(const float* __restrict__ xproj,
                                                     unsigned short* __restrict__ hbuf,
                                                     float* __restrict__ c_ws,
                                                     const unsigned short* __restrict__ Wh,
                                                     unsigned int* __restrict__ bar,
                                                     float* __restrict__ out,
                                                     int t0, int T) {
    __shared__ float red[8192];   // 32KB: [wv:4][32][64]
    int tid = threadIdx.x, lane = tid & 63, wv = tid >> 6;
    int l15 = lane & 15, l4 = lane >> 4;
    int wg = blockIdx.x;
    int mhalf = wg & 1;
    int cg = wg >> 1;
    int j0 = cg * 16;
    unsigned int* mybar = bar + mhalf * 32;

    bf16x8 w[8][4];
#pragma unroll
    for (int ks = 0; ks < 8; ++ks)
#pragma unroll
        for (int g = 0; g < 4; ++g) {
            int n = g * 1024 + j0 + l15;
            int k = wv * 256 + ks * 32 + l4 * 8;
            w[ks][g] = *(const bf16x8*)(Wh + (size_t)n * 1024 + k);
        }
#pragma unroll
    for (int ks = 0; ks < 8; ++ks)
#pragma unroll
        for (int g = 0; g < 4; ++g)
            asm volatile("" : "+a"(w[ks][g]));

    float c_reg[2];
    int bq[2];
#pragma unroll
    for (int pi = 0; pi < 2; ++pi) {
        int p = wv * 2 + pi, m = p >> 2, r = p & 3;
        bq[pi] = mhalf * 32 + m * 16 + l4 * 4 + r;
        c_reg[pi] = c_ws[(size_t)bq[pi] * 1024 + j0 + l15];
    }

    float4 xp_cur[2], xp_nxt[2];
#pragma unroll
    for (int pi = 0; pi < 2; ++pi)
        xp_cur[pi] = *(const float4*)(xproj + (size_t)bq[pi] * 4096 + (j0 + l15) * 4);

    for (int tl = 0; tl < T; ++tl) {
        int ts = t0 + tl;
        int par = ts & 1;
        const unsigned short* hb = hbuf + (size_t)par * 65536;

        bf16x8 af[2][8];
#pragma unroll
        for (int m = 0; m < 2; ++m) {
            int row = mhalf * 32 + m * 16 + l15;
            const unsigned short* rp = hb + (size_t)row * 1024 + wv * 256 + l4 * 8;
#pragma unroll
            for (int ks = 0; ks < 8; ++ks) {
                unsigned long long* p = (unsigned long long*)(rp + ks * 32);
                union { unsigned long long q[2]; bf16x8 v; } u;
                u.q[0] = __hip_atomic_load(p,     __ATOMIC_RELAXED, __HIP_MEMORY_SCOPE_AGENT);
                u.q[1] = __hip_atomic_load(p + 1, __ATOMIC_RELAXED, __HIP_MEMORY_SCOPE_AGENT);
                af[m][ks] = u.v;
            }
        }

        f32x4 acc[2][4] = {};
#pragma unroll
        for (int ks = 0; ks < 8; ++ks)
#pragma unroll
            for (int m = 0; m < 2; ++m)
#pragma unroll
                for (int g = 0; g < 4; ++g)
                    acc[m][g] = __builtin_amdgcn_mfma_f32_16x16x32_bf16(af[m][ks], w[ks][g], acc[m][g], 0, 0, 0);

#pragma unroll
        for (int m = 0; m < 2; ++m)
#pragma unroll
            for (int g = 0; g < 4; ++g)
#pragma unroll
                for (int r = 0; r < 4; ++r)
                    red[(wv * 32 + m * 16 + g * 4 + r) * 64 + lane] = acc[m][g][r];
        __syncthreads();

        float yv[2];
#pragma unroll
        for (int pi = 0; pi < 2; ++pi) {
            int p = wv * 2 + pi, m = p >> 2, r = p & 3;
            int b = bq[pi];
            int j = j0 + l15;
            const float* xpf = (const float*)&xp_cur[pi];
            float pre[4];
#pragma unroll
            for (int g = 0; g < 4; ++g) {
                int s = m * 16 + g * 4 + r;
                pre[g] = red[s * 64 + lane] + red[(32 + s) * 64 + lane] +
                         red[(64 + s) * 64 + lane] + red[(96 + s) * 64 + lane] + xpf[g];
            }
            float I = fast_sigmoid(pre[0]);
            float F = fast_sigmoid(pre[1]);
            float G = fast_tanh(pre[2]);
            float O = fast_sigmoid(pre[3]);
            float c = F * c_reg[pi] + I * G;
            c_reg[pi] = c;
            float y = O * fast_tanh(c);
            yv[pi] = y;
            __hip_atomic_store(hbuf + (size_t)(par ^ 1) * 65536 + (size_t)b * 1024 + j,
                               f2bf(y), __ATOMIC_RELAXED, __HIP_MEMORY_SCOPE_AGENT);
        }

        __syncthreads();   // drain h stores before signaling

        int tln = (tl + 1 < T) ? tl + 1 : tl;
#pragma unroll
        for (int pi = 0; pi < 2; ++pi)
            xp_nxt[pi] = *(const float4*)(xproj + (size_t)(tln * 64 + bq[pi]) * 4096 + (j0 + l15) * 4);

        if (tid == 0) {
            __hip_atomic_fetch_add(mybar, 1u, __ATOMIC_RELAXED, __HIP_MEMORY_SCOPE_AGENT);
            unsigned target = (unsigned)(ts + 1) * 64u;
            while (__hip_atomic_load(mybar, __ATOMIC_RELAXED, __HIP_MEMORY_SCOPE_AGENT) < target)
                __builtin_amdgcn_s_sleep(1);
        }
        __syncthreads();

#pragma unroll
        for (int pi = 0; pi < 2; ++pi) {
            int b = bq[pi];
            int j = j0 + l15;
            out[(size_t)(ts * 64 + b) * 1024 + j] = yv[pi];
            if (ts == 1023) {
                out[67108864u + (size_t)b * 1024 + j] = yv[pi];             // hT
                out[67108864u + 65536u + (size_t)b * 1024 + j] = c_reg[pi]; // cT
            }
        }
        xp_cur[0] = xp_nxt[0];
        xp_cur[1] = xp_nxt[1];
    }
#pragma unroll
    for (int pi = 0; pi < 2; ++pi)
        c_ws[(size_t)bq[pi] * 1024 + j0 + l15] = c_reg[pi];
}

extern "C" void kernel_launch(void* const* d_in, const int* in_sizes, int n_in,
                              void* d_out, int out_size, void* d_ws, size_t ws_size,
                              hipStream_t stream) {
    (void)in_sizes; (void)n_in; (void)out_size;
    const float* Xt = (const float*)d_in[0];
    const float* W[8]; for (int i = 0; i < 8; ++i) W[i] = (const float*)d_in[1 + i];
    const float* Bv[8]; for (int i = 0; i < 8; ++i) Bv[i] = (const float*)d_in[9 + i];
    float* out = (float*)d_out;
    uint8_t* ws = (uint8_t*)d_ws;

    unsigned int*  bar   = (unsigned int*)(ws + 0);            // [0,512) real, [512,1024) probe
    unsigned int*  pbar  = (unsigned int*)(ws + 512);
    float*         bias  = (float*)(ws + 1024);                // 16384 B
    unsigned short* hbuf = (unsigned short*)(ws + 17408);      // [2][64][1024] bf16 (256 KB)
    float*         c_ws  = (float*)(ws + 279552);              // [64][1024] fp32 (256 KB)
    unsigned short* Wx   = (unsigned short*)(ws + 541696);     // 8 MB
    unsigned short* Wh   = (unsigned short*)(ws + 8930304);    // 8 MB
    unsigned int*  phbuf = (unsigned int*)(ws + 17318912);     // 256 KB probe h
    float*         psink = (float*)(ws + 17581056);            // 128 KB probe sink
    float*         xproj = (float*)(ws + 17712128);            // [T*64][4096] fp32

    size_t avail = ws_size > 17712128 ? ws_size - 17712128 : 0;
    int T = 4;
    for (int t = 1024; t >= 4; t >>= 1)
        if ((size_t)t * 1048576ull <= avail) { T = t; break; }

    init_kernel<<<64, 256, 0, stream>>>(Bv[0], Bv[1], Bv[2], Bv[3], Bv[4], Bv[5], Bv[6], Bv[7],
                                        bias, hbuf, c_ws, bar, phbuf);
    prep_weights<<<4096, 256, 0, stream>>>(W[0], W[1], W[2], W[3], W[4], W[5], W[6], W[7], Wx, Wh);

    // ---- probes: decompose the 6 us/step (read their dur_us in rocprof) ----
    probe_sync<<<128, 256, 0, stream>>>(pbar, 512);
    probe_rt  <<<128, 256, 0, stream>>>(phbuf, psink, 512);
    probe_comp<<<128, 256, 0, stream>>>(psink + 32768, 512);

    int nch = 1024 / T;
    for (int c = 0; c < nch; ++c) {
        xproj_gemm<<<dim3(32, T / 2), 256, 0, stream>>>(Xt + (size_t)c * T * 65536, Wx, bias, xproj);
        lstm_steps<<<128, 256, 0, stream>>>(xproj, hbuf, c_ws, Wh, bar, out, c * T, T);
    }
}

// Round 12
// 8176.575 us; speedup vs baseline: 1.6899x; 1.3525x over previous
//
#include <hip/hip_runtime.h>
#include <hip/hip_bf16.h>
#include <stdint.h>

// LSTM: S=1024, B=64, D=1024, H=1024. fp32 in/out, bf16 MFMA internally.
// out = [Yt (S*B*H) | hT (B*H) | cT (B*H)] fp32.
// R12: R7-measured-best recurrence + combining-tree arrive (8 groups x 8 WGs
// per mhalf; last group-arriver bumps root; all poll root). Probes removed.

typedef __attribute__((ext_vector_type(8))) short bf16x8;
typedef __attribute__((ext_vector_type(4))) float f32x4;

__device__ __forceinline__ unsigned short f2bf(float f) {
    unsigned u = __builtin_bit_cast(unsigned, f);
    return (unsigned short)((u + 0x7fffu + ((u >> 16) & 1u)) >> 16);
}
__device__ __forceinline__ float fast_sigmoid(float x) {
    return __builtin_amdgcn_rcpf(1.f + __expf(-x));
}
__device__ __forceinline__ float fast_tanh(float x) {
    float xc = fminf(fmaxf(x, -9.f), 9.f);
    float e = __expf(2.f * xc);
    return (e - 1.f) * __builtin_amdgcn_rcpf(e + 1.f);
}

// ---------------- init: bias fusion + state zeroing ----------------
__global__ void init_kernel(const float* __restrict__ iiB, const float* __restrict__ hiB,
                            const float* __restrict__ ifB, const float* __restrict__ hfB,
                            const float* __restrict__ igB, const float* __restrict__ hgB,
                            const float* __restrict__ ioB, const float* __restrict__ hoB,
                            float* __restrict__ bias, unsigned short* __restrict__ hbuf0,
                            float* __restrict__ c_ws, unsigned int* __restrict__ bar) {
    int tid = blockIdx.x * 256 + threadIdx.x;   // grid 64 x 256 = 16384
    if (tid < 1024) bar[tid] = 0u;   // per mhalf: 8 group ctrs (stride 32) + root at +256
    if (tid < 4096) {
        int g = tid >> 10, j = tid & 1023;
        const float* ib = (g == 0 ? iiB : g == 1 ? ifB : g == 2 ? igB : ioB);
        const float* hb = (g == 0 ? hiB : g == 1 ? hfB : g == 2 ? hgB : hoB);
        bias[tid] = ib[j] + hb[j];
    }
    for (int i = tid; i < 65536; i += 16384) {
        __hip_atomic_store(hbuf0 + i, (unsigned short)0, __ATOMIC_RELAXED, __HIP_MEMORY_SCOPE_AGENT);
        c_ws[i] = 0.f;
    }
}

// ---------------- weights -> bf16, gate-stacked n = g*1024 + j ----------------
__global__ void prep_weights(const float* __restrict__ iiW, const float* __restrict__ hiW,
                             const float* __restrict__ ifW, const float* __restrict__ hfW,
                             const float* __restrict__ igW, const float* __restrict__ hgW,
                             const float* __restrict__ ioW, const float* __restrict__ hoW,
                             unsigned short* __restrict__ Wx, unsigned short* __restrict__ Wh) {
    int n = blockIdx.x;               // 0..4095
    int g = n >> 10, j = n & 1023;
    const float* wx = (g == 0 ? iiW : g == 1 ? ifW : g == 2 ? igW : ioW) + (size_t)j * 1024;
    const float* wh = (g == 0 ? hiW : g == 1 ? hfW : g == 2 ? hgW : hoW) + (size_t)j * 1024;
    int k = threadIdx.x * 4;
    float4 a = *(const float4*)(wx + k);
    float4 b = *(const float4*)(wh + k);
    ushort4 ra = { f2bf(a.x), f2bf(a.y), f2bf(a.z), f2bf(a.w) };
    ushort4 rb = { f2bf(b.x), f2bf(b.y), f2bf(b.z), f2bf(b.w) };
    *(ushort4*)(Wx + (size_t)n * 1024 + k) = ra;
    *(ushort4*)(Wh + (size_t)n * 1024 + k) = rb;
}

// ---------------- Xproj GEMM: C[M][.] = A[M][1024] @ Wx^T + bias ----------------
// 128x128 tile, BK=32, 4 waves each 64x64 (4x4 of 16x16x32 bf16 MFMA).
// Output column PERMUTED: gate-stacked n (= g*1024+j) lands at column j*4+g.
__global__ __launch_bounds__(256, 2) void xproj_gemm(const float* __restrict__ A,
                                                     const unsigned short* __restrict__ Wx,
                                                     const float* __restrict__ bias,
                                                     float* __restrict__ C) {
    __shared__ __align__(16) unsigned short Asm[128 * 32];  // 8KB, XOR-swizzled slots
    __shared__ __align__(16) unsigned short Bsm[128 * 32];  // 8KB
    int tid = threadIdx.x;
    int lane = tid & 63, wv = tid >> 6;
    int l15 = lane & 15, l4 = lane >> 4;
    int wrow = wv >> 1, wcol = wv & 1;
    int bn0 = blockIdx.x * 128, bm0 = blockIdx.y * 128;
    f32x4 acc[4][4] = {};

    for (int kk = 0; kk < 32; ++kk) {
        int k0 = kk * 32;
        __syncthreads();
#pragma unroll
        for (int it = 0; it < 2; ++it) {
            int tau = it * 256 + tid;
            int row = tau >> 2, slot = tau & 3;
            const float* src = A + (size_t)(bm0 + row) * 1024 + k0 + slot * 8;
            float4 x0 = *(const float4*)src;
            float4 x1 = *(const float4*)(src + 4);
            bf16x8 pk;
            pk[0] = (short)f2bf(x0.x); pk[1] = (short)f2bf(x0.y);
            pk[2] = (short)f2bf(x0.z); pk[3] = (short)f2bf(x0.w);
            pk[4] = (short)f2bf(x1.x); pk[5] = (short)f2bf(x1.y);
            pk[6] = (short)f2bf(x1.z); pk[7] = (short)f2bf(x1.w);
            int dslot = slot ^ (row & 3);
            *(bf16x8*)((char*)Asm + row * 64 + dslot * 16) = pk;
        }
#pragma unroll
        for (int it = 0; it < 2; ++it) {
            int tau = it * 256 + tid;
            int row = tau >> 2, slot = tau & 3;
            int sslot = slot ^ (row & 3);
            const unsigned short* src = Wx + (size_t)(bn0 + row) * 1024 + k0 + sslot * 8;
            char* ldsb = (char*)Bsm + it * 4096 + wv * 1024;
            __builtin_amdgcn_global_load_lds((const __attribute__((address_space(1))) void*)src,
                                             (__attribute__((address_space(3))) void*)ldsb, 16, 0, 0);
        }
        __syncthreads();
        bf16x8 af[4], bfv[4];
#pragma unroll
        for (int i = 0; i < 4; ++i) {
            int rowa = wrow * 64 + i * 16 + l15;
            int sa = l4 ^ (rowa & 3);
            af[i] = *(const bf16x8*)((const char*)Asm + rowa * 64 + sa * 16);
            int rowb = wcol * 64 + i * 16 + l15;
            int sb = l4 ^ (rowb & 3);
            bfv[i] = *(const bf16x8*)((const char*)Bsm + rowb * 64 + sb * 16);
        }
#pragma unroll
        for (int i = 0; i < 4; ++i)
#pragma unroll
            for (int j = 0; j < 4; ++j)
                acc[i][j] = __builtin_amdgcn_mfma_f32_16x16x32_bf16(af[i], bfv[j], acc[i][j], 0, 0, 0);
    }
#pragma unroll
    for (int i = 0; i < 4; ++i) {
        int m = bm0 + wrow * 64 + i * 16 + l4 * 4;
#pragma unroll
        for (int j = 0; j < 4; ++j) {
            int n = bn0 + wcol * 64 + j * 16 + l15;
            int col = (n & 1023) * 4 + (n >> 10);
            float bs = bias[n];
#pragma unroll
            for (int r = 0; r < 4; ++r)
                C[(size_t)(m + r) * 4096 + col] = acc[i][j][r] + bs;
        }
    }
}

// ---------------- persistent recurrent kernel (one chunk of T steps) ----------------
// 128 WGs x 256 thr. WG (cg, mhalf): hidden units j0=16*cg..+16, all 4 gates,
// batch rows mhalf*32..+32. Waves K-split (256 each); Wh in AGPRs.
// Barrier: combining tree -- 8 group counters (8 WGs each) + root, per mhalf.
__global__ __launch_bounds__(256, 1) void lstm_steps(const float* __restrict__ xproj,
                                                     unsigned short* __restrict__ hbuf,
                                                     float* __restrict__ c_ws,
                                                     const unsigned short* __restrict__ Wh,
                                                     unsigned int* __restrict__ bar,
                                                     float* __restrict__ out,
                                                     int t0, int T) {
    __shared__ float red[8192];   // 32KB: [wv:4][32][64]
    int tid = threadIdx.x, lane = tid & 63, wv = tid >> 6;
    int l15 = lane & 15, l4 = lane >> 4;
    int wg = blockIdx.x;
    int mhalf = wg & 1;
    int cg = wg >> 1;
    int j0 = cg * 16;
    unsigned int* mybar = bar + mhalf * 512;        // 2KB per mhalf
    unsigned int* grpc  = mybar + (cg >> 3) * 32;   // own 128B line per group
    unsigned int* root  = mybar + 256;              // root line

    bf16x8 w[8][4];
#pragma unroll
    for (int ks = 0; ks < 8; ++ks)
#pragma unroll
        for (int g = 0; g < 4; ++g) {
            int n = g * 1024 + j0 + l15;
            int k = wv * 256 + ks * 32 + l4 * 8;
            w[ks][g] = *(const bf16x8*)(Wh + (size_t)n * 1024 + k);
        }
#pragma unroll
    for (int ks = 0; ks < 8; ++ks)
#pragma unroll
        for (int g = 0; g < 4; ++g)
            asm volatile("" : "+a"(w[ks][g]));

    float c_reg[2];
    int bq[2];
#pragma unroll
    for (int pi = 0; pi < 2; ++pi) {
        int p = wv * 2 + pi, m = p >> 2, r = p & 3;
        bq[pi] = mhalf * 32 + m * 16 + l4 * 4 + r;
        c_reg[pi] = c_ws[(size_t)bq[pi] * 1024 + j0 + l15];
    }

    float4 xp_cur[2], xp_nxt[2];
#pragma unroll
    for (int pi = 0; pi < 2; ++pi)
        xp_cur[pi] = *(const float4*)(xproj + (size_t)bq[pi] * 4096 + (j0 + l15) * 4);

    for (int tl = 0; tl < T; ++tl) {
        int ts = t0 + tl;
        int par = ts & 1;
        const unsigned short* hb = hbuf + (size_t)par * 65536;

        bf16x8 af[2][8];
#pragma unroll
        for (int m = 0; m < 2; ++m) {
            int row = mhalf * 32 + m * 16 + l15;
            const unsigned short* rp = hb + (size_t)row * 1024 + wv * 256 + l4 * 8;
#pragma unroll
            for (int ks = 0; ks < 8; ++ks) {
                unsigned long long* p = (unsigned long long*)(rp + ks * 32);
                union { unsigned long long q[2]; bf16x8 v; } u;
                u.q[0] = __hip_atomic_load(p,     __ATOMIC_RELAXED, __HIP_MEMORY_SCOPE_AGENT);
                u.q[1] = __hip_atomic_load(p + 1, __ATOMIC_RELAXED, __HIP_MEMORY_SCOPE_AGENT);
                af[m][ks] = u.v;
            }
        }

        f32x4 acc[2][4] = {};
#pragma unroll
        for (int ks = 0; ks < 8; ++ks)
#pragma unroll
            for (int m = 0; m < 2; ++m)
#pragma unroll
                for (int g = 0; g < 4; ++g)
                    acc[m][g] = __builtin_amdgcn_mfma_f32_16x16x32_bf16(af[m][ks], w[ks][g], acc[m][g], 0, 0, 0);

#pragma unroll
        for (int m = 0; m < 2; ++m)
#pragma unroll
            for (int g = 0; g < 4; ++g)
#pragma unroll
                for (int r = 0; r < 4; ++r)
                    red[(wv * 32 + m * 16 + g * 4 + r) * 64 + lane] = acc[m][g][r];
        __syncthreads();

        float yv[2];
#pragma unroll
        for (int pi = 0; pi < 2; ++pi) {
            int p = wv * 2 + pi, m = p >> 2, r = p & 3;
            int b = bq[pi];
            int j = j0 + l15;
            const float* xpf = (const float*)&xp_cur[pi];
            float pre[4];
#pragma unroll
            for (int g = 0; g < 4; ++g) {
                int s = m * 16 + g * 4 + r;
                pre[g] = red[s * 64 + lane] + red[(32 + s) * 64 + lane] +
                         red[(64 + s) * 64 + lane] + red[(96 + s) * 64 + lane] + xpf[g];
            }
            float I = fast_sigmoid(pre[0]);
            float F = fast_sigmoid(pre[1]);
            float G = fast_tanh(pre[2]);
            float O = fast_sigmoid(pre[3]);
            float c = F * c_reg[pi] + I * G;
            c_reg[pi] = c;
            float y = O * fast_tanh(c);
            yv[pi] = y;
            __hip_atomic_store(hbuf + (size_t)(par ^ 1) * 65536 + (size_t)b * 1024 + j,
                               f2bf(y), __ATOMIC_RELAXED, __HIP_MEMORY_SCOPE_AGENT);
        }

        __syncthreads();   // drain h stores (L3 ack) before signaling

        int tln = (tl + 1 < T) ? tl + 1 : tl;
#pragma unroll
        for (int pi = 0; pi < 2; ++pi)
            xp_nxt[pi] = *(const float4*)(xproj + (size_t)(tln * 64 + bq[pi]) * 4096 + (j0 + l15) * 4);

        if (tid == 0) {
            // combining-tree arrive: group RMW; last group-arriver bumps root
            unsigned old = __hip_atomic_fetch_add(grpc, 1u, __ATOMIC_RELAXED, __HIP_MEMORY_SCOPE_AGENT);
            if (old == (unsigned)(ts + 1) * 8u - 1u)
                __hip_atomic_fetch_add(root, 1u, __ATOMIC_RELAXED, __HIP_MEMORY_SCOPE_AGENT);
            unsigned target = (unsigned)(ts + 1) * 8u;
            while (__hip_atomic_load(root, __ATOMIC_RELAXED, __HIP_MEMORY_SCOPE_AGENT) < target)
                __builtin_amdgcn_s_sleep(1);
        }
        __syncthreads();

#pragma unroll
        for (int pi = 0; pi < 2; ++pi) {
            int b = bq[pi];
            int j = j0 + l15;
            out[(size_t)(ts * 64 + b) * 1024 + j] = yv[pi];
            if (ts == 1023) {
                out[67108864u + (size_t)b * 1024 + j] = yv[pi];             // hT
                out[67108864u + 65536u + (size_t)b * 1024 + j] = c_reg[pi]; // cT
            }
        }
        xp_cur[0] = xp_nxt[0];
        xp_cur[1] = xp_nxt[1];
    }
#pragma unroll
    for (int pi = 0; pi < 2; ++pi)
        c_ws[(size_t)bq[pi] * 1024 + j0 + l15] = c_reg[pi];
}

extern "C" void kernel_launch(void* const* d_in, const int* in_sizes, int n_in,
                              void* d_out, int out_size, void* d_ws, size_t ws_size,
                              hipStream_t stream) {
    (void)in_sizes; (void)n_in; (void)out_size;
    const float* Xt = (const float*)d_in[0];
    const float* W[8]; for (int i = 0; i < 8; ++i) W[i] = (const float*)d_in[1 + i];
    const float* Bv[8]; for (int i = 0; i < 8; ++i) Bv[i] = (const float*)d_in[9 + i];
    float* out = (float*)d_out;
    uint8_t* ws = (uint8_t*)d_ws;

    unsigned int*  bar   = (unsigned int*)(ws + 0);            // 4KB tree counters
    float*         bias  = (float*)(ws + 4096);                // 16KB
    unsigned short* hbuf = (unsigned short*)(ws + 20480);      // [2][64][1024] bf16 (256KB)
    float*         c_ws  = (float*)(ws + 282624);              // [64][1024] fp32 (256KB)
    unsigned short* Wx   = (unsigned short*)(ws + 544768);     // 8MB
    unsigned short* Wh   = (unsigned short*)(ws + 8933376);    // 8MB
    float*         xproj = (float*)(ws + 17321984);            // [T*64][4096] fp32

    size_t avail = ws_size > 17321984 ? ws_size - 17321984 : 0;
    int T = 4;
    for (int t = 1024; t >= 4; t >>= 1)
        if ((size_t)t * 1048576ull <= avail) { T = t; break; }

    init_kernel<<<64, 256, 0, stream>>>(Bv[0], Bv[1], Bv[2], Bv[3], Bv[4], Bv[5], Bv[6], Bv[7],
                                        bias, hbuf, c_ws, bar);
    prep_weights<<<4096, 256, 0, stream>>>(W[0], W[1], W[2], W[3], W[4], W[5], W[6], W[7], Wx, Wh);

    int nch = 1024 / T;
    for (int c = 0; c < nch; ++c) {
        xproj_gemm<<<dim3(32, T / 2), 256, 0, stream>>>(Xt + (size_t)c * T * 65536, Wx, bias, xproj);
        lstm_steps<<<128, 256, 0, stream>>>(xproj, hbuf, c_ws, Wh, bar, out, c * T, T);
    }
}